// Round 3
// baseline (1268.537 us; speedup 1.0000x reference)
//
#include <hip/hip_runtime.h>
#include <math.h>

#define F_IN 512
#define HID  16
#define NCLS 40
#define NPB  128      // nodes per bucket (c >> 7)
#define NPW  512      // partition workgroups
#define MAXBUK 1024

typedef __attribute__((ext_vector_type(8))) short short8;
typedef __attribute__((ext_vector_type(4))) float floatx4;

// ---------- bf16 helpers ----------
__device__ __forceinline__ unsigned short bf16_rne(float f) {
    unsigned u = __float_as_uint(f);
    u += 0x7fffu + ((u >> 16) & 1u);
    return (unsigned short)(u >> 16);
}
__device__ __forceinline__ float bf16_f32(unsigned short s) {
    return __uint_as_float(((unsigned)s) << 16);
}

// ---------- Phase A: per-WG bucket histogram (LDS atomics only) ----------
__global__ void k_hist(const int* __restrict__ col, int* __restrict__ g_hist,
                       int E, int chunk, int nbuk) {
    __shared__ int h[MAXBUK];
    for (int i = threadIdx.x; i < nbuk; i += 256) h[i] = 0;
    __syncthreads();
    int s = blockIdx.x * chunk;
    int e = s + chunk; if (e > E) e = E;
    for (int j = s + threadIdx.x; j < e; j += 256)
        atomicAdd(&h[col[j] >> 7], 1);
    __syncthreads();
    for (int i = threadIdx.x; i < nbuk; i += 256)
        g_hist[(size_t)blockIdx.x * nbuk + i] = h[i];   // w-major, coalesced
}

// ---------- per-bucket totals ----------
__global__ void k_tot(const int* __restrict__ g_hist, int* __restrict__ tot,
                      int nbuk, int W) {
    int b = blockIdx.x * 256 + threadIdx.x;
    if (b < nbuk) {
        int s = 0;
        for (int w = 0; w < W; ++w) s += g_hist[(size_t)w * nbuk + b];
        tot[b] = s;
    }
}

// ---------- exclusive scan of totals -> bucket base ----------
__global__ void k_base(const int* __restrict__ tot, int* __restrict__ base,
                       int nbuk, int E) {
    __shared__ int s[1024];
    int t = threadIdx.x;
    int v = (t < nbuk) ? tot[t] : 0;
    s[t] = v; __syncthreads();
    for (int off = 1; off < 1024; off <<= 1) {
        int a = (t >= off) ? s[t - off] : 0;
        __syncthreads(); s[t] += a; __syncthreads();
    }
    if (t < nbuk) base[t] = s[t] - v;
    if (t == 0) base[nbuk] = E;
}

// ---------- per-(wg,bucket) offsets: scan along w for each bucket ----------
__global__ void k_offs(int* __restrict__ g_hist, const int* __restrict__ base,
                       int nbuk) {
    __shared__ int s[256];
    int b = blockIdx.x, t = threadIdx.x;
    int v0 = g_hist[(size_t)(2 * t)     * nbuk + b];
    int v1 = g_hist[(size_t)(2 * t + 1) * nbuk + b];
    int pair = v0 + v1;
    s[t] = pair; __syncthreads();
    for (int off = 1; off < 256; off <<= 1) {
        int a = (t >= off) ? s[t - off] : 0;
        __syncthreads(); s[t] += a; __syncthreads();
    }
    int excl = s[t] - pair;
    int bb = base[b];
    g_hist[(size_t)(2 * t)     * nbuk + b] = bb + excl;
    g_hist[(size_t)(2 * t + 1) * nbuk + b] = bb + excl + v0;
}

// ---------- Phase C: scatter edges into bucket-grouped array (LDS cursors) ----------
// record: x = r | (local_c << 17)   (r < 2^17, local_c < 128), y = bits(w)
__global__ void k_part(const int* __restrict__ row, const int* __restrict__ col,
                       const float* __restrict__ w, const int* __restrict__ offs,
                       uint2* __restrict__ sedge, int E, int chunk, int nbuk) {
    __shared__ int cur[MAXBUK];
    for (int i = threadIdx.x; i < nbuk; i += 256)
        cur[i] = offs[(size_t)blockIdx.x * nbuk + i];
    __syncthreads();
    int s = blockIdx.x * chunk;
    int e = s + chunk; if (e > E) e = E;
    for (int j = s + threadIdx.x; j < e; j += 256) {
        int r = row[j], c = col[j];
        int b = c >> 7;
        int pos = atomicAdd(&cur[b], 1);       // LDS atomic
        uint2 rec;
        rec.x = (unsigned)r | ((unsigned)(c & (NPB - 1)) << 17);
        rec.y = __float_as_uint(w[j]);
        sedge[pos] = rec;
    }
}

// ---------- per-bucket degree -> dis (LDS fp32 atomics) ----------
__global__ void k_degb(const uint2* __restrict__ sedge, const int* __restrict__ base,
                       float* __restrict__ dis, int N) {
    __shared__ float deg[NPB];
    int b = blockIdx.x;
    if (threadIdx.x < NPB) deg[threadIdx.x] = 1.0f;   // self loop
    __syncthreads();
    int s = base[b], e = base[b + 1];
    for (int j = s + threadIdx.x; j < e; j += 256) {
        uint2 rec = sedge[j];
        atomicAdd(&deg[rec.x >> 17], __uint_as_float(rec.y));
    }
    __syncthreads();
    int n = b * NPB + threadIdx.x;
    if (threadIdx.x < NPB && n < N) dis[n] = rsqrtf(deg[threadIdx.x]);
}

// ---------- per-bucket: rewrite w -> norm = dis[r]*w*dis[c] ----------
__global__ void k_normb(uint2* __restrict__ sedge, const int* __restrict__ base,
                        const float* __restrict__ dis, int N) {
    __shared__ float dloc[NPB];
    int b = blockIdx.x;
    if (threadIdx.x < NPB) {
        int n = b * NPB + threadIdx.x;
        dloc[threadIdx.x] = (n < N) ? dis[n] : 0.f;
    }
    __syncthreads();
    int s = base[b], e = base[b + 1];
    for (int j = s + threadIdx.x; j < e; j += 256) {
        uint2 rec = sedge[j];
        int r = rec.x & 0x1FFFF;
        float nrm = dis[r] * __uint_as_float(rec.y) * dloc[rec.x >> 17];
        rec.y = __float_as_uint(nrm);
        sedge[j] = rec;
    }
}

// ---------- h1 = x @ W1 via 16x16x32 bf16 MFMA, hi/lo split ----------
__global__ void k_xw1_mfma(const float* __restrict__ x, const float* __restrict__ W1,
                           float* __restrict__ h1, int N, int nTiles) {
    __shared__ unsigned short wh[HID][F_IN + 8];
    __shared__ unsigned short wl[HID][F_IN + 8];
    for (int f = threadIdx.x; f < F_IN * HID; f += 256) {
        int k = f >> 4, h = f & 15;
        float v = W1[f];
        unsigned short hhi = bf16_rne(v);
        float rem = v - bf16_f32(hhi);
        wh[h][k] = hhi;
        wl[h][k] = (unsigned short)(__float_as_uint(rem) >> 16);
    }
    __syncthreads();

    int wave = threadIdx.x >> 6;
    int lane = threadIdx.x & 63;
    int tile = blockIdx.x * 4 + wave;
    if (tile >= nTiles) return;

    int m    = lane & 15;
    int quad = lane >> 4;
    int node = tile * 16 + m;
    if (node >= N) node = N - 1;
    const float* xr = x + (size_t)node * F_IN;

    floatx4 acc = {0.f, 0.f, 0.f, 0.f};

    #pragma unroll 4
    for (int s = 0; s < F_IN / 32; ++s) {
        int k0 = s * 32 + quad * 8;
        float4 v0 = *(const float4*)(xr + k0);
        float4 v1 = *(const float4*)(xr + k0 + 4);
        float xv[8] = {v0.x, v0.y, v0.z, v0.w, v1.x, v1.y, v1.z, v1.w};
        short8 ah, al;
        #pragma unroll
        for (int j = 0; j < 8; ++j) {
            unsigned short hhi = bf16_rne(xv[j]);
            float rem = xv[j] - bf16_f32(hhi);
            ah[j] = (short)hhi;
            al[j] = (short)(unsigned short)(__float_as_uint(rem) >> 16);
        }
        short8 bh = *(const short8*)&wh[m][k0];
        short8 bl = *(const short8*)&wl[m][k0];
        acc = __builtin_amdgcn_mfma_f32_16x16x32_bf16(ah, bh, acc, 0, 0, 0);
        acc = __builtin_amdgcn_mfma_f32_16x16x32_bf16(ah, bl, acc, 0, 0, 0);
        acc = __builtin_amdgcn_mfma_f32_16x16x32_bf16(al, bh, acc, 0, 0, 0);
    }

    int h = lane & 15;
    #pragma unroll
    for (int r = 0; r < 4; ++r) {
        int nrow = tile * 16 + quad * 4 + r;
        if (nrow < N) h1[(size_t)nrow * HID + h] = acc[r];
    }
}

// ---------- aggregation: one WG per bucket, LDS fp32 accumulator ----------
__global__ void k_agg(const uint2* __restrict__ sedge, const int* __restrict__ base,
                      const float* __restrict__ dis, const float* __restrict__ src,
                      const float* __restrict__ bias, float* __restrict__ dst,
                      int N, int relu) {
    __shared__ float acc[NPB * HID];   // 8 KB
    int b = blockIdx.x;
    int n0 = b * NPB;
    for (int i = threadIdx.x; i < NPB * HID; i += 256) {
        int n = n0 + (i >> 4);
        float v = 0.f;
        if (n < N) {
            float d = dis[n];
            v = src[(size_t)n * HID + (i & 15)] * d * d;   // self loop
        }
        acc[i] = v;
    }
    __syncthreads();
    int s = base[b], e = base[b + 1];
    int h = threadIdx.x & 15;
    for (int j = s + (threadIdx.x >> 4); j < e; j += 16) {
        uint2 rec = sedge[j];
        int r  = rec.x & 0x1FFFF;
        int lc = rec.x >> 17;
        float v = src[(size_t)r * HID + h] * __uint_as_float(rec.y);
        atomicAdd(&acc[lc * HID + h], v);   // LDS atomic
    }
    __syncthreads();
    for (int i = threadIdx.x; i < NPB * HID; i += 256) {
        int n = n0 + (i >> 4);
        if (n < N) {
            float v = acc[i];
            if (bias) v += bias[i & 15];
            if (relu) v = v > 0.f ? v : 0.f;
            dst[(size_t)n * HID + (i & 15)] = v;
        }
    }
}

// ---------- out = log_softmax(agg2 @ W2 + b2) ----------
__global__ void k_final(const float* __restrict__ B, const float* __restrict__ W2,
                        const float* __restrict__ b2, float* __restrict__ out, int N) {
    __shared__ float w2s[HID * NCLS];
    __shared__ float b2s[NCLS];
    for (int f = threadIdx.x; f < HID * NCLS; f += 256) w2s[f] = W2[f];
    if (threadIdx.x < NCLS) b2s[threadIdx.x] = b2[threadIdx.x];
    __syncthreads();
    int nd = blockIdx.x * 256 + threadIdx.x;
    if (nd < N) {
        float a[HID];
        const float4* ap = (const float4*)(B + (size_t)nd * HID);
        #pragma unroll
        for (int q = 0; q < 4; ++q) {
            float4 v = ap[q];
            a[q * 4 + 0] = v.x; a[q * 4 + 1] = v.y;
            a[q * 4 + 2] = v.z; a[q * 4 + 3] = v.w;
        }
        float y[NCLS];
        #pragma unroll
        for (int c = 0; c < NCLS; ++c) y[c] = b2s[c];
        #pragma unroll
        for (int hh = 0; hh < HID; ++hh) {
            float av = a[hh];
            #pragma unroll
            for (int c = 0; c < NCLS; ++c) y[c] = fmaf(av, w2s[hh * NCLS + c], y[c]);
        }
        float m = y[0];
        #pragma unroll
        for (int c = 1; c < NCLS; ++c) m = fmaxf(m, y[c]);
        float sum = 0.f;
        #pragma unroll
        for (int c = 0; c < NCLS; ++c) sum += expf(y[c] - m);
        float bse = m + logf(sum);
        float* op = out + (size_t)nd * NCLS;
        #pragma unroll
        for (int c = 0; c < NCLS; ++c) op[c] = y[c] - bse;
    }
}

// ---------- launch ----------
extern "C" void kernel_launch(void* const* d_in, const int* in_sizes, int n_in,
                              void* d_out, int out_size, void* d_ws, size_t ws_size,
                              hipStream_t stream) {
    const float* x  = (const float*)d_in[0];
    const int*   ei = (const int*)d_in[1];
    const float* ew = (const float*)d_in[2];
    const float* W1 = (const float*)d_in[3];
    const float* b1 = (const float*)d_in[4];
    const float* W2 = (const float*)d_in[5];
    const float* b2 = (const float*)d_in[6];
    float* out = (float*)d_out;

    int N = in_sizes[0] / F_IN;      // 100000
    int E = in_sizes[2];             // 3200000
    const int* row = ei;
    const int* col = ei + E;

    int nbuk  = (N + NPB - 1) / NPB;         // 782
    int chunk = (E + NPW - 1) / NPW;         // 6250

    // workspace layout
    char* w = (char*)d_ws;
    uint2* sedge  = (uint2*)w;                     size_t off = (size_t)E * 8;
    float* A      = (float*)(w + off);             off += (size_t)N * HID * 4;
    float* Bb     = (float*)(w + off);             off += (size_t)N * HID * 4;
    float* dis    = (float*)(w + off);             off += (size_t)N * 4;
    int*   g_hist = (int*)(w + off);               off += (size_t)NPW * nbuk * 4;
    int*   tot    = (int*)(w + off);               off += (size_t)nbuk * 4;
    int*   base   = (int*)(w + off);               off += (size_t)(nbuk + 1) * 4;

    dim3 blk(256);

    // partition build (no global atomics)
    k_hist<<<dim3(NPW), blk, 0, stream>>>(col, g_hist, E, chunk, nbuk);
    k_tot<<<dim3((nbuk + 255) / 256), blk, 0, stream>>>(g_hist, tot, nbuk, NPW);
    k_base<<<dim3(1), dim3(1024), 0, stream>>>(tot, base, nbuk, E);
    k_offs<<<dim3(nbuk), blk, 0, stream>>>(g_hist, base, nbuk);
    k_part<<<dim3(NPW), blk, 0, stream>>>(row, col, ew, g_hist, sedge, E, chunk, nbuk);

    // degree + norm
    k_degb<<<dim3(nbuk), blk, 0, stream>>>(sedge, base, dis, N);
    k_normb<<<dim3(nbuk), blk, 0, stream>>>(sedge, base, dis, N);

    // h1 = x @ W1 (MFMA)
    int nTiles = (N + 15) / 16;
    int gT = (nTiles + 3) / 4;
    k_xw1_mfma<<<dim3(gT), blk, 0, stream>>>(x, W1, A, N, nTiles);

    // z1 = relu(Ahat*h1 + b1) ; agg2 = Ahat*z1
    k_agg<<<dim3(nbuk), blk, 0, stream>>>(sedge, base, dis, A, b1, Bb, N, 1);
    k_agg<<<dim3(nbuk), blk, 0, stream>>>(sedge, base, dis, Bb, (const float*)nullptr, A, N, 0);

    // out
    k_final<<<dim3((N + 255) / 256), blk, 0, stream>>>(A, W2, b2, out, N);
}

// Round 4
// 1261.152 us; speedup vs baseline: 1.0059x; 1.0059x over previous
//
#include <hip/hip_runtime.h>
#include <math.h>

#define F_IN 512
#define HID  16
#define NCLS 40
#define NPB  128      // nodes per bucket (c >> 7)
#define NPW  512      // partition workgroups
#define MAXBUK 1024
#define BATCH 8

typedef __attribute__((ext_vector_type(8))) short short8;
typedef __attribute__((ext_vector_type(4))) float floatx4;

// ---------- bf16 helpers ----------
__device__ __forceinline__ unsigned short bf16_rne(float f) {
    unsigned u = __float_as_uint(f);
    u += 0x7fffu + ((u >> 16) & 1u);
    return (unsigned short)(u >> 16);
}
__device__ __forceinline__ float bf16_f32(unsigned short s) {
    return __uint_as_float(((unsigned)s) << 16);
}

// ---------- Phase A: per-WG bucket histogram (LDS atomics only) ----------
__global__ void k_hist(const int* __restrict__ col, int* __restrict__ g_hist,
                       int E, int chunk, int nbuk) {
    __shared__ int h[MAXBUK];
    for (int i = threadIdx.x; i < nbuk; i += 256) h[i] = 0;
    __syncthreads();
    int s = blockIdx.x * chunk;
    int e = s + chunk; if (e > E) e = E;
    for (int j = s + threadIdx.x; j < e; j += 256)
        atomicAdd(&h[col[j] >> 7], 1);
    __syncthreads();
    for (int i = threadIdx.x; i < nbuk; i += 256)
        g_hist[(size_t)blockIdx.x * nbuk + i] = h[i];   // w-major, coalesced
}

// ---------- per-bucket totals ----------
__global__ void k_tot(const int* __restrict__ g_hist, int* __restrict__ tot,
                      int nbuk, int W) {
    int b = blockIdx.x * 256 + threadIdx.x;
    if (b < nbuk) {
        int s = 0;
        for (int w = 0; w < W; ++w) s += g_hist[(size_t)w * nbuk + b];
        tot[b] = s;
    }
}

// ---------- exclusive scan of totals -> bucket base ----------
__global__ void k_base(const int* __restrict__ tot, int* __restrict__ base,
                       int nbuk, int E) {
    __shared__ int s[1024];
    int t = threadIdx.x;
    int v = (t < nbuk) ? tot[t] : 0;
    s[t] = v; __syncthreads();
    for (int off = 1; off < 1024; off <<= 1) {
        int a = (t >= off) ? s[t - off] : 0;
        __syncthreads(); s[t] += a; __syncthreads();
    }
    if (t < nbuk) base[t] = s[t] - v;
    if (t == 0) base[nbuk] = E;
}

// ---------- per-(wg,bucket) offsets: scan along w for each bucket ----------
__global__ void k_offs(int* __restrict__ g_hist, const int* __restrict__ base,
                       int nbuk) {
    __shared__ int s[256];
    int b = blockIdx.x, t = threadIdx.x;
    int v0 = g_hist[(size_t)(2 * t)     * nbuk + b];
    int v1 = g_hist[(size_t)(2 * t + 1) * nbuk + b];
    int pair = v0 + v1;
    s[t] = pair; __syncthreads();
    for (int off = 1; off < 256; off <<= 1) {
        int a = (t >= off) ? s[t - off] : 0;
        __syncthreads(); s[t] += a; __syncthreads();
    }
    int excl = s[t] - pair;
    int bb = base[b];
    g_hist[(size_t)(2 * t)     * nbuk + b] = bb + excl;
    g_hist[(size_t)(2 * t + 1) * nbuk + b] = bb + excl + v0;
}

// ---------- Phase C: scatter edges into bucket-grouped array (LDS cursors) ----------
// record: x = r | (local_c << 17)   (r < 2^17, local_c < 128), y = bits(w)
__global__ void k_part(const int* __restrict__ row, const int* __restrict__ col,
                       const float* __restrict__ w, const int* __restrict__ offs,
                       uint2* __restrict__ sedge, int E, int chunk, int nbuk) {
    __shared__ int cur[MAXBUK];
    for (int i = threadIdx.x; i < nbuk; i += 256)
        cur[i] = offs[(size_t)blockIdx.x * nbuk + i];
    __syncthreads();
    int s = blockIdx.x * chunk;
    int e = s + chunk; if (e > E) e = E;
    for (int j = s + threadIdx.x; j < e; j += 256) {
        int r = row[j], c = col[j];
        int b = c >> 7;
        int pos = atomicAdd(&cur[b], 1);       // LDS atomic
        uint2 rec;
        rec.x = (unsigned)r | ((unsigned)(c & (NPB - 1)) << 17);
        rec.y = __float_as_uint(w[j]);
        sedge[pos] = rec;
    }
}

// ---------- per-bucket degree -> dis (LDS fp32 atomics) ----------
__global__ void k_degb(const uint2* __restrict__ sedge, const int* __restrict__ base,
                       float* __restrict__ dis, int N) {
    __shared__ float deg[NPB];
    int b = blockIdx.x;
    if (threadIdx.x < NPB) deg[threadIdx.x] = 1.0f;   // self loop
    __syncthreads();
    int s = base[b], e = base[b + 1];
    for (int j = s + threadIdx.x; j < e; j += 256) {
        uint2 rec = sedge[j];
        atomicAdd(&deg[rec.x >> 17], __uint_as_float(rec.y));
    }
    __syncthreads();
    int n = b * NPB + threadIdx.x;
    if (threadIdx.x < NPB && n < N) dis[n] = rsqrtf(deg[threadIdx.x]);
}

// ---------- per-bucket: rewrite w -> norm = dis[r]*w*dis[c] ----------
__global__ void k_normb(uint2* __restrict__ sedge, const int* __restrict__ base,
                        const float* __restrict__ dis, int N) {
    __shared__ float dloc[NPB];
    int b = blockIdx.x;
    if (threadIdx.x < NPB) {
        int n = b * NPB + threadIdx.x;
        dloc[threadIdx.x] = (n < N) ? dis[n] : 0.f;
    }
    __syncthreads();
    int s = base[b], e = base[b + 1];
    for (int j = s + threadIdx.x; j < e; j += 256) {
        uint2 rec = sedge[j];
        int r = rec.x & 0x1FFFF;
        float nrm = dis[r] * __uint_as_float(rec.y) * dloc[rec.x >> 17];
        rec.y = __float_as_uint(nrm);
        sedge[j] = rec;
    }
}

// ---------- h1 = x @ W1 via 16x16x32 bf16 MFMA, hi/lo split ----------
__global__ void k_xw1_mfma(const float* __restrict__ x, const float* __restrict__ W1,
                           float* __restrict__ h1, int N, int nTiles) {
    __shared__ unsigned short wh[HID][F_IN + 8];
    __shared__ unsigned short wl[HID][F_IN + 8];
    for (int f = threadIdx.x; f < F_IN * HID; f += 256) {
        int k = f >> 4, h = f & 15;
        float v = W1[f];
        unsigned short hhi = bf16_rne(v);
        float rem = v - bf16_f32(hhi);
        wh[h][k] = hhi;
        wl[h][k] = (unsigned short)(__float_as_uint(rem) >> 16);
    }
    __syncthreads();

    int wave = threadIdx.x >> 6;
    int lane = threadIdx.x & 63;
    int tile = blockIdx.x * 4 + wave;
    if (tile >= nTiles) return;

    int m    = lane & 15;
    int quad = lane >> 4;
    int node = tile * 16 + m;
    if (node >= N) node = N - 1;
    const float* xr = x + (size_t)node * F_IN;

    floatx4 acc = {0.f, 0.f, 0.f, 0.f};

    #pragma unroll 4
    for (int s = 0; s < F_IN / 32; ++s) {
        int k0 = s * 32 + quad * 8;
        float4 v0 = *(const float4*)(xr + k0);
        float4 v1 = *(const float4*)(xr + k0 + 4);
        float xv[8] = {v0.x, v0.y, v0.z, v0.w, v1.x, v1.y, v1.z, v1.w};
        short8 ah, al;
        #pragma unroll
        for (int j = 0; j < 8; ++j) {
            unsigned short hhi = bf16_rne(xv[j]);
            float rem = xv[j] - bf16_f32(hhi);
            ah[j] = (short)hhi;
            al[j] = (short)(unsigned short)(__float_as_uint(rem) >> 16);
        }
        short8 bh = *(const short8*)&wh[m][k0];
        short8 bl = *(const short8*)&wl[m][k0];
        acc = __builtin_amdgcn_mfma_f32_16x16x32_bf16(ah, bh, acc, 0, 0, 0);
        acc = __builtin_amdgcn_mfma_f32_16x16x32_bf16(ah, bl, acc, 0, 0, 0);
        acc = __builtin_amdgcn_mfma_f32_16x16x32_bf16(al, bh, acc, 0, 0, 0);
    }

    int h = lane & 15;
    #pragma unroll
    for (int r = 0; r < 4; ++r) {
        int nrow = tile * 16 + quad * 4 + r;
        if (nrow < N) h1[(size_t)nrow * HID + h] = acc[r];
    }
}

// ---------- aggregation: one WG per bucket, LDS fp32 accumulator ----------
// 512 threads = 32 edge slots x 16 channels; BATCH=8 prefetched edges per slot
// breaks the load->gather->atomic dependent chain (32 outstanding VMEM/wave).
__global__ __launch_bounds__(512) void k_agg(
        const uint2* __restrict__ sedge, const int* __restrict__ base,
        const float* __restrict__ dis, const float* __restrict__ src,
        const float* __restrict__ bias, float* __restrict__ dst,
        int N, int relu) {
    __shared__ float acc[NPB * HID];   // 8 KB
    int b = blockIdx.x;
    int n0 = b * NPB;
    for (int i = threadIdx.x; i < NPB * HID; i += 512) {
        int n = n0 + (i >> 4);
        float v = 0.f;
        if (n < N) {
            float d = dis[n];
            v = src[(size_t)n * HID + (i & 15)] * d * d;   // self loop
        }
        acc[i] = v;
    }
    __syncthreads();
    int s = base[b], e = base[b + 1];
    int g = threadIdx.x >> 4;   // edge slot 0..31
    int h = threadIdx.x & 15;
    for (int j = s + g; j < e; j += 32 * BATCH) {
        uint2 rec[BATCH];
        int   ok[BATCH];
        #pragma unroll
        for (int q = 0; q < BATCH; ++q) {
            int jj = j + 32 * q;
            ok[q] = jj < e;
            rec[q] = sedge[ok[q] ? jj : j];   // j always valid here
        }
        float v[BATCH];
        #pragma unroll
        for (int q = 0; q < BATCH; ++q)
            v[q] = src[(size_t)(rec[q].x & 0x1FFFF) * HID + h];
        #pragma unroll
        for (int q = 0; q < BATCH; ++q)
            if (ok[q])
                atomicAdd(&acc[(rec[q].x >> 17) * HID + h],
                          v[q] * __uint_as_float(rec[q].y));
    }
    __syncthreads();
    for (int i = threadIdx.x; i < NPB * HID; i += 512) {
        int n = n0 + (i >> 4);
        if (n < N) {
            float v = acc[i];
            if (bias) v += bias[i & 15];
            if (relu) v = v > 0.f ? v : 0.f;
            dst[(size_t)n * HID + (i & 15)] = v;
        }
    }
}

// ---------- out = log_softmax(agg2 @ W2 + b2) ----------
__global__ void k_final(const float* __restrict__ B, const float* __restrict__ W2,
                        const float* __restrict__ b2, float* __restrict__ out, int N) {
    __shared__ float w2s[HID * NCLS];
    __shared__ float b2s[NCLS];
    for (int f = threadIdx.x; f < HID * NCLS; f += 256) w2s[f] = W2[f];
    if (threadIdx.x < NCLS) b2s[threadIdx.x] = b2[threadIdx.x];
    __syncthreads();
    int nd = blockIdx.x * 256 + threadIdx.x;
    if (nd < N) {
        float a[HID];
        const float4* ap = (const float4*)(B + (size_t)nd * HID);
        #pragma unroll
        for (int q = 0; q < 4; ++q) {
            float4 v = ap[q];
            a[q * 4 + 0] = v.x; a[q * 4 + 1] = v.y;
            a[q * 4 + 2] = v.z; a[q * 4 + 3] = v.w;
        }
        float y[NCLS];
        #pragma unroll
        for (int c = 0; c < NCLS; ++c) y[c] = b2s[c];
        #pragma unroll
        for (int hh = 0; hh < HID; ++hh) {
            float av = a[hh];
            #pragma unroll
            for (int c = 0; c < NCLS; ++c) y[c] = fmaf(av, w2s[hh * NCLS + c], y[c]);
        }
        float m = y[0];
        #pragma unroll
        for (int c = 1; c < NCLS; ++c) m = fmaxf(m, y[c]);
        float sum = 0.f;
        #pragma unroll
        for (int c = 0; c < NCLS; ++c) sum += expf(y[c] - m);
        float bse = m + logf(sum);
        float* op = out + (size_t)nd * NCLS;
        #pragma unroll
        for (int c = 0; c < NCLS; ++c) op[c] = y[c] - bse;
    }
}

// ---------- launch ----------
extern "C" void kernel_launch(void* const* d_in, const int* in_sizes, int n_in,
                              void* d_out, int out_size, void* d_ws, size_t ws_size,
                              hipStream_t stream) {
    const float* x  = (const float*)d_in[0];
    const int*   ei = (const int*)d_in[1];
    const float* ew = (const float*)d_in[2];
    const float* W1 = (const float*)d_in[3];
    const float* b1 = (const float*)d_in[4];
    const float* W2 = (const float*)d_in[5];
    const float* b2 = (const float*)d_in[6];
    float* out = (float*)d_out;

    int N = in_sizes[0] / F_IN;      // 100000
    int E = in_sizes[2];             // 3200000
    const int* row = ei;
    const int* col = ei + E;

    int nbuk  = (N + NPB - 1) / NPB;         // 782
    int chunk = (E + NPW - 1) / NPW;         // 6250

    // workspace layout
    char* w = (char*)d_ws;
    uint2* sedge  = (uint2*)w;                     size_t off = (size_t)E * 8;
    float* A      = (float*)(w + off);             off += (size_t)N * HID * 4;
    float* Bb     = (float*)(w + off);             off += (size_t)N * HID * 4;
    float* dis    = (float*)(w + off);             off += (size_t)N * 4;
    int*   g_hist = (int*)(w + off);               off += (size_t)NPW * nbuk * 4;
    int*   tot    = (int*)(w + off);               off += (size_t)nbuk * 4;
    int*   base   = (int*)(w + off);               off += (size_t)(nbuk + 1) * 4;

    dim3 blk(256);

    // partition build (no global atomics)
    k_hist<<<dim3(NPW), blk, 0, stream>>>(col, g_hist, E, chunk, nbuk);
    k_tot<<<dim3((nbuk + 255) / 256), blk, 0, stream>>>(g_hist, tot, nbuk, NPW);
    k_base<<<dim3(1), dim3(1024), 0, stream>>>(tot, base, nbuk, E);
    k_offs<<<dim3(nbuk), blk, 0, stream>>>(g_hist, base, nbuk);
    k_part<<<dim3(NPW), blk, 0, stream>>>(row, col, ew, g_hist, sedge, E, chunk, nbuk);

    // degree + norm
    k_degb<<<dim3(nbuk), blk, 0, stream>>>(sedge, base, dis, N);
    k_normb<<<dim3(nbuk), blk, 0, stream>>>(sedge, base, dis, N);

    // h1 = x @ W1 (MFMA)
    int nTiles = (N + 15) / 16;
    int gT = (nTiles + 3) / 4;
    k_xw1_mfma<<<dim3(gT), blk, 0, stream>>>(x, W1, A, N, nTiles);

    // z1 = relu(Ahat*h1 + b1) ; agg2 = Ahat*z1
    k_agg<<<dim3(nbuk), dim3(512), 0, stream>>>(sedge, base, dis, A, b1, Bb, N, 1);
    k_agg<<<dim3(nbuk), dim3(512), 0, stream>>>(sedge, base, dis, Bb, (const float*)nullptr, A, N, 0);

    // out
    k_final<<<dim3((N + 255) / 256), blk, 0, stream>>>(A, W2, b2, out, N);
}

// Round 5
// 695.772 us; speedup vs baseline: 1.8232x; 1.8126x over previous
//
#include <hip/hip_runtime.h>
#include <math.h>

#define F_IN 512
#define HID  16
#define NCLS 40
#define NPB  128      // nodes per bucket (c >> 7)
#define NPW  512      // partition workgroups
#define MAXBUK 1024

typedef __attribute__((ext_vector_type(8))) short short8;
typedef __attribute__((ext_vector_type(4))) float floatx4;

// ---------- bf16 helpers ----------
__device__ __forceinline__ unsigned short bf16_rne(float f) {
    unsigned u = __float_as_uint(f);
    u += 0x7fffu + ((u >> 16) & 1u);
    return (unsigned short)(u >> 16);
}
__device__ __forceinline__ float bf16_f32(unsigned short s) {
    return __uint_as_float(((unsigned)s) << 16);
}

// ---------- Phase A: per-WG bucket histogram (LDS atomics only) ----------
__global__ void k_hist(const int* __restrict__ col, int* __restrict__ g_hist,
                       int E, int chunk, int nbuk) {
    __shared__ int h[MAXBUK];
    for (int i = threadIdx.x; i < nbuk; i += 256) h[i] = 0;
    __syncthreads();
    int s = blockIdx.x * chunk;
    int e = s + chunk; if (e > E) e = E;
    for (int j = s + threadIdx.x; j < e; j += 256)
        atomicAdd(&h[col[j] >> 7], 1);
    __syncthreads();
    for (int i = threadIdx.x; i < nbuk; i += 256)
        g_hist[(size_t)blockIdx.x * nbuk + i] = h[i];
}

// ---------- per-bucket totals ----------
__global__ void k_tot(const int* __restrict__ g_hist, int* __restrict__ tot,
                      int nbuk, int W) {
    int b = blockIdx.x * 256 + threadIdx.x;
    if (b < nbuk) {
        int s = 0;
        for (int w = 0; w < W; ++w) s += g_hist[(size_t)w * nbuk + b];
        tot[b] = s;
    }
}

// ---------- exclusive scan of totals -> bucket base ----------
__global__ void k_base(const int* __restrict__ tot, int* __restrict__ base,
                       int nbuk, int E) {
    __shared__ int s[1024];
    int t = threadIdx.x;
    int v = (t < nbuk) ? tot[t] : 0;
    s[t] = v; __syncthreads();
    for (int off = 1; off < 1024; off <<= 1) {
        int a = (t >= off) ? s[t - off] : 0;
        __syncthreads(); s[t] += a; __syncthreads();
    }
    if (t < nbuk) base[t] = s[t] - v;
    if (t == 0) base[nbuk] = E;
}

// ---------- per-(wg,bucket) offsets ----------
__global__ void k_offs(int* __restrict__ g_hist, const int* __restrict__ base,
                       int nbuk) {
    __shared__ int s[256];
    int b = blockIdx.x, t = threadIdx.x;
    int v0 = g_hist[(size_t)(2 * t)     * nbuk + b];
    int v1 = g_hist[(size_t)(2 * t + 1) * nbuk + b];
    int pair = v0 + v1;
    s[t] = pair; __syncthreads();
    for (int off = 1; off < 256; off <<= 1) {
        int a = (t >= off) ? s[t - off] : 0;
        __syncthreads(); s[t] += a; __syncthreads();
    }
    int excl = s[t] - pair;
    int bb = base[b];
    g_hist[(size_t)(2 * t)     * nbuk + b] = bb + excl;
    g_hist[(size_t)(2 * t + 1) * nbuk + b] = bb + excl + v0;
}

// ---------- Phase C: scatter edges into bucket-grouped array ----------
// record: x = r | (local_c << 17), y = bits(w)
__global__ void k_part(const int* __restrict__ row, const int* __restrict__ col,
                       const float* __restrict__ w, const int* __restrict__ offs,
                       uint2* __restrict__ sedge, int E, int chunk, int nbuk) {
    __shared__ int cur[MAXBUK];
    for (int i = threadIdx.x; i < nbuk; i += 256)
        cur[i] = offs[(size_t)blockIdx.x * nbuk + i];
    __syncthreads();
    int s = blockIdx.x * chunk;
    int e = s + chunk; if (e > E) e = E;
    for (int j = s + threadIdx.x; j < e; j += 256) {
        int r = row[j], c = col[j];
        int b = c >> 7;
        int pos = atomicAdd(&cur[b], 1);
        uint2 rec;
        rec.x = (unsigned)r | ((unsigned)(c & (NPB - 1)) << 17);
        rec.y = __float_as_uint(w[j]);
        sedge[pos] = rec;
    }
}

// ---------- Phase D: per-bucket counting sort -> per-node CSR + dis ----------
// one WG per bucket; 128 bins. Outputs sedge2 (.x=r, .y=w), rowptr, dis.
__global__ void k_sort(const uint2* __restrict__ sedge, const int* __restrict__ base,
                       uint2* __restrict__ sedge2, int* __restrict__ rowptr,
                       float* __restrict__ dis, int N, int nbuk) {
    __shared__ int   cnt[NPB];
    __shared__ float wdeg[NPB];
    __shared__ int   scn[NPB];
    __shared__ int   cur[NPB];
    int b = blockIdx.x, t = threadIdx.x;
    if (t < NPB) { cnt[t] = 0; wdeg[t] = 1.0f; }   // self-loop weight 1
    __syncthreads();
    int s = base[b], e = base[b + 1];
    for (int j = s + t; j < e; j += 256) {
        uint2 rec = sedge[j];
        int lc = rec.x >> 17;
        atomicAdd(&cnt[lc], 1);
        atomicAdd(&wdeg[lc], __uint_as_float(rec.y));
    }
    __syncthreads();
    if (t < NPB) scn[t] = cnt[t];
    __syncthreads();
    for (int off = 1; off < NPB; off <<= 1) {
        int a = (t < NPB && t >= off) ? scn[t - off] : 0;
        __syncthreads();
        if (t < NPB) scn[t] += a;
        __syncthreads();
    }
    if (t < NPB) {
        int excl = scn[t] - cnt[t];
        cur[t] = s + excl;
        int n = b * NPB + t;
        if (n < N) {
            rowptr[n] = s + excl;
            dis[n] = rsqrtf(wdeg[t]);
        }
    }
    __syncthreads();
    for (int j = s + t; j < e; j += 256) {
        uint2 rec = sedge[j];
        int lc = rec.x >> 17;
        int pos = atomicAdd(&cur[lc], 1);
        sedge2[pos] = make_uint2(rec.x & 0x1FFFF, rec.y);
    }
    if (b == nbuk - 1 && t == 0) rowptr[N] = e;
}

// ---------- fold dis[r] into edge weight: y = w * dis[r] ----------
__global__ void k_norm(uint2* __restrict__ sedge2, const float* __restrict__ dis, int E) {
    int i = blockIdx.x * 256 + threadIdx.x;
    if (i < E) {
        uint2 r = sedge2[i];
        r.y = __float_as_uint(__uint_as_float(r.y) * dis[r.x]);
        sedge2[i] = r;
    }
}

// ---------- h1 = x @ W1 via 16x16x32 bf16 MFMA, hi/lo split ----------
__global__ void k_xw1_mfma(const float* __restrict__ x, const float* __restrict__ W1,
                           float* __restrict__ h1, int N, int nTiles) {
    __shared__ unsigned short wh[HID][F_IN + 8];
    __shared__ unsigned short wl[HID][F_IN + 8];
    for (int f = threadIdx.x; f < F_IN * HID; f += 256) {
        int k = f >> 4, h = f & 15;
        float v = W1[f];
        unsigned short hhi = bf16_rne(v);
        float rem = v - bf16_f32(hhi);
        wh[h][k] = hhi;
        wl[h][k] = (unsigned short)(__float_as_uint(rem) >> 16);
    }
    __syncthreads();

    int wave = threadIdx.x >> 6;
    int lane = threadIdx.x & 63;
    int tile = blockIdx.x * 4 + wave;
    if (tile >= nTiles) return;

    int m    = lane & 15;
    int quad = lane >> 4;
    int node = tile * 16 + m;
    if (node >= N) node = N - 1;
    const float* xr = x + (size_t)node * F_IN;

    floatx4 acc = {0.f, 0.f, 0.f, 0.f};

    #pragma unroll 4
    for (int s = 0; s < F_IN / 32; ++s) {
        int k0 = s * 32 + quad * 8;
        float4 v0 = *(const float4*)(xr + k0);
        float4 v1 = *(const float4*)(xr + k0 + 4);
        float xv[8] = {v0.x, v0.y, v0.z, v0.w, v1.x, v1.y, v1.z, v1.w};
        short8 ah, al;
        #pragma unroll
        for (int j = 0; j < 8; ++j) {
            unsigned short hhi = bf16_rne(xv[j]);
            float rem = xv[j] - bf16_f32(hhi);
            ah[j] = (short)hhi;
            al[j] = (short)(unsigned short)(__float_as_uint(rem) >> 16);
        }
        short8 bh = *(const short8*)&wh[m][k0];
        short8 bl = *(const short8*)&wl[m][k0];
        acc = __builtin_amdgcn_mfma_f32_16x16x32_bf16(ah, bh, acc, 0, 0, 0);
        acc = __builtin_amdgcn_mfma_f32_16x16x32_bf16(ah, bl, acc, 0, 0, 0);
        acc = __builtin_amdgcn_mfma_f32_16x16x32_bf16(al, bh, acc, 0, 0, 0);
    }

    int h = lane & 15;
    #pragma unroll
    for (int r = 0; r < 4; ++r) {
        int nrow = tile * 16 + quad * 4 + r;
        if (nrow < N) h1[(size_t)nrow * HID + h] = acc[r];
    }
}

// ---------- atomic-free aggregation: 16-lane group per node ----------
// acc_h = sum_e (w*dis[r]) * src[r][h];  dst = dis[c]*acc + dis[c]^2*src[c] (+bias, relu)
__global__ void k_agg2(const uint2* __restrict__ sedge2, const int* __restrict__ rowptr,
                       const float* __restrict__ dis, const float* __restrict__ src,
                       const float* __restrict__ bias, float* __restrict__ dst,
                       int N, int relu) {
    int g = (blockIdx.x * 256 + threadIdx.x) >> 4;   // node
    int h = threadIdx.x & 15;
    if (g >= N) return;
    int e0 = rowptr[g], e1 = rowptr[g + 1];
    float acc = 0.f;
    int j = e0;
    for (; j + 4 <= e1; j += 4) {
        uint2 r0 = sedge2[j + 0];
        uint2 r1 = sedge2[j + 1];
        uint2 r2 = sedge2[j + 2];
        uint2 r3 = sedge2[j + 3];
        float v0 = src[(size_t)r0.x * HID + h];
        float v1 = src[(size_t)r1.x * HID + h];
        float v2 = src[(size_t)r2.x * HID + h];
        float v3 = src[(size_t)r3.x * HID + h];
        acc = fmaf(__uint_as_float(r0.y), v0, acc);
        acc = fmaf(__uint_as_float(r1.y), v1, acc);
        acc = fmaf(__uint_as_float(r2.y), v2, acc);
        acc = fmaf(__uint_as_float(r3.y), v3, acc);
    }
    for (; j < e1; ++j) {
        uint2 r = sedge2[j];
        acc = fmaf(__uint_as_float(r.y), src[(size_t)r.x * HID + h], acc);
    }
    float d = dis[g];
    float v = d * acc + d * d * src[(size_t)g * HID + h];
    if (bias) v += bias[h];
    if (relu) v = v > 0.f ? v : 0.f;
    dst[(size_t)g * HID + h] = v;
}

// ---------- out = log_softmax(agg2 @ W2 + b2) ----------
__global__ void k_final(const float* __restrict__ B, const float* __restrict__ W2,
                        const float* __restrict__ b2, float* __restrict__ out, int N) {
    __shared__ float w2s[HID * NCLS];
    __shared__ float b2s[NCLS];
    for (int f = threadIdx.x; f < HID * NCLS; f += 256) w2s[f] = W2[f];
    if (threadIdx.x < NCLS) b2s[threadIdx.x] = b2[threadIdx.x];
    __syncthreads();
    int nd = blockIdx.x * 256 + threadIdx.x;
    if (nd < N) {
        float a[HID];
        const float4* ap = (const float4*)(B + (size_t)nd * HID);
        #pragma unroll
        for (int q = 0; q < 4; ++q) {
            float4 v = ap[q];
            a[q * 4 + 0] = v.x; a[q * 4 + 1] = v.y;
            a[q * 4 + 2] = v.z; a[q * 4 + 3] = v.w;
        }
        float y[NCLS];
        #pragma unroll
        for (int c = 0; c < NCLS; ++c) y[c] = b2s[c];
        #pragma unroll
        for (int hh = 0; hh < HID; ++hh) {
            float av = a[hh];
            #pragma unroll
            for (int c = 0; c < NCLS; ++c) y[c] = fmaf(av, w2s[hh * NCLS + c], y[c]);
        }
        float m = y[0];
        #pragma unroll
        for (int c = 1; c < NCLS; ++c) m = fmaxf(m, y[c]);
        float sum = 0.f;
        #pragma unroll
        for (int c = 0; c < NCLS; ++c) sum += expf(y[c] - m);
        float bse = m + logf(sum);
        float* op = out + (size_t)nd * NCLS;
        #pragma unroll
        for (int c = 0; c < NCLS; ++c) op[c] = y[c] - bse;
    }
}

// ---------- launch ----------
extern "C" void kernel_launch(void* const* d_in, const int* in_sizes, int n_in,
                              void* d_out, int out_size, void* d_ws, size_t ws_size,
                              hipStream_t stream) {
    const float* x  = (const float*)d_in[0];
    const int*   ei = (const int*)d_in[1];
    const float* ew = (const float*)d_in[2];
    const float* W1 = (const float*)d_in[3];
    const float* b1 = (const float*)d_in[4];
    const float* W2 = (const float*)d_in[5];
    const float* b2 = (const float*)d_in[6];
    float* out = (float*)d_out;

    int N = in_sizes[0] / F_IN;      // 100000
    int E = in_sizes[2];             // 3200000
    const int* row = ei;
    const int* col = ei + E;

    int nbuk  = (N + NPB - 1) / NPB;         // 782
    int chunk = (E + NPW - 1) / NPW;         // 6250

    // workspace layout
    char* w = (char*)d_ws;
    uint2* sedge  = (uint2*)w;                     size_t off = (size_t)E * 8;
    uint2* sedge2 = (uint2*)(w + off);             off += (size_t)E * 8;
    float* A      = (float*)(w + off);             off += (size_t)N * HID * 4;
    float* Bb     = (float*)(w + off);             off += (size_t)N * HID * 4;
    float* dis    = (float*)(w + off);             off += (size_t)N * 4;
    int*   rowptr = (int*)(w + off);               off += (size_t)(N + 1) * 4;
    int*   g_hist = (int*)(w + off);               off += (size_t)NPW * nbuk * 4;
    int*   tot    = (int*)(w + off);               off += (size_t)nbuk * 4;
    int*   base   = (int*)(w + off);               off += (size_t)(nbuk + 1) * 4;

    dim3 blk(256);

    // partition build (bucket level)
    k_hist<<<dim3(NPW), blk, 0, stream>>>(col, g_hist, E, chunk, nbuk);
    k_tot<<<dim3((nbuk + 255) / 256), blk, 0, stream>>>(g_hist, tot, nbuk, NPW);
    k_base<<<dim3(1), dim3(1024), 0, stream>>>(tot, base, nbuk, E);
    k_offs<<<dim3(nbuk), blk, 0, stream>>>(g_hist, base, nbuk);
    k_part<<<dim3(NPW), blk, 0, stream>>>(row, col, ew, g_hist, sedge, E, chunk, nbuk);

    // node-level CSR + dis, then fold dis[r] into weights
    k_sort<<<dim3(nbuk), blk, 0, stream>>>(sedge, base, sedge2, rowptr, dis, N, nbuk);
    k_norm<<<dim3((E + 255) / 256), blk, 0, stream>>>(sedge2, dis, E);

    // h1 = x @ W1 (MFMA)
    int nTiles = (N + 15) / 16;
    int gT = (nTiles + 3) / 4;
    k_xw1_mfma<<<dim3(gT), blk, 0, stream>>>(x, W1, A, N, nTiles);

    // z1 = relu(Ahat*h1 + b1) ; agg2 = Ahat*z1
    int gA = (N * HID + 255) / 256;
    k_agg2<<<dim3(gA), blk, 0, stream>>>(sedge2, rowptr, dis, A, b1, Bb, N, 1);
    k_agg2<<<dim3(gA), blk, 0, stream>>>(sedge2, rowptr, dis, Bb, (const float*)nullptr, A, N, 0);

    // out
    k_final<<<dim3((N + 255) / 256), blk, 0, stream>>>(A, W2, b2, out, N);
}